// Round 3
// baseline (428.312 us; speedup 1.0000x reference)
//
#include <hip/hip_runtime.h>

#define F_FEATS 50000
#define BATCH 16
#define EMBED_DIM 128
#define OUT_DIM 1024
#define TOPK 300

// ---------------------------------------------------------------------------
// Kernel 1: exact top-300 per row via 4-pass radix select on float bits
// (monotonic for non-negative floats), then compaction.
// Tie-break at the threshold value: keep lowest indices (matches lax.top_k).
// One block per batch row, 1024 threads.
// ---------------------------------------------------------------------------
__global__ __launch_bounds__(1024) void topk_kernel(const float* __restrict__ sae,
                                                    int* __restrict__ idxL,
                                                    float* __restrict__ valL) {
  const int b = blockIdx.x;
  const int tid = threadIdx.x;
  const float* row = sae + (size_t)b * F_FEATS;

  __shared__ unsigned int whist[16][256];   // per-wave privatized histograms
  __shared__ unsigned int shist[256];
  __shared__ unsigned int s_prefix, s_rem;
  __shared__ unsigned int s_cnt_gt, s_cnt_eq;
  __shared__ unsigned int eq_idx[256];

  if (tid == 0) { s_prefix = 0u; s_rem = TOPK; }
  const int wave = tid >> 6;
  __syncthreads();

  for (int pass = 0; pass < 4; ++pass) {
    const int shift = 24 - 8 * pass;
    for (int v = tid; v < 16 * 256; v += 1024) ((unsigned int*)whist)[v] = 0u;
    __syncthreads();
    const unsigned int prefix = s_prefix;
    for (int i = tid; i < F_FEATS; i += 1024) {
      unsigned int k = __float_as_uint(row[i]);
      bool match = (pass == 0) || ((k >> (shift + 8)) == prefix);
      if (match) atomicAdd(&whist[wave][(k >> shift) & 255u], 1u);
    }
    __syncthreads();
    if (tid < 256) {
      unsigned int s = 0;
      #pragma unroll
      for (int w = 0; w < 16; ++w) s += whist[w][tid];
      shist[tid] = s;
    }
    __syncthreads();
    if (tid == 0) {
      unsigned int rem = s_rem, cum = 0u;
      int v;
      for (v = 255; v > 0; --v) {
        if (cum + shist[v] >= rem) break;
        cum += shist[v];
      }
      s_prefix = (prefix << 8) | (unsigned int)v;
      s_rem = rem - cum;   // >= 1 by construction
    }
    __syncthreads();
  }

  const unsigned int T = s_prefix;   // exact 32-bit key of the 300th largest
  if (tid == 0) { s_cnt_gt = 0u; s_cnt_eq = 0u; }
  __syncthreads();

  for (int i = tid; i < F_FEATS; i += 1024) {
    float x = row[i];
    unsigned int k = __float_as_uint(x);
    if (k > T) {
      unsigned int p = atomicAdd(&s_cnt_gt, 1u);
      idxL[b * TOPK + p] = i;
      valL[b * TOPK + p] = x;
    } else if (k == T) {
      unsigned int p = atomicAdd(&s_cnt_eq, 1u);
      if (p < 256u) eq_idx[p] = (unsigned int)i;
    }
  }
  __syncthreads();

  if (tid == 0) {
    int cgt = (int)s_cnt_gt;
    int need = TOPK - cgt;                  // how many ==T elements to keep
    int m = (int)s_cnt_eq; if (m > 256) m = 256;
    for (int n = 0; n < need; ++n) {
      int best = -1; unsigned int bi = 0x7fffffffu;
      for (int q = 0; q < m; ++q) {
        if (eq_idx[q] < bi) { bi = eq_idx[q]; best = q; }
      }
      int outi = 0; float outv = 0.f;
      if (best >= 0) { eq_idx[best] = 0x7fffffffu; outi = (int)bi; outv = __uint_as_float(T); }
      idxL[b * TOPK + cgt + n] = outi;
      valL[b * TOPK + cgt + n] = outv;
    }
  }
}

// ---------------------------------------------------------------------------
// Kernel 2: FM interaction + 2-layer MLP, fused. One block per batch row,
// 512 threads = 4 k-phases x 128 dims. Chunked idx prefetch breaks the
// idx->gather dependency chain.
// ---------------------------------------------------------------------------
__global__ __launch_bounds__(512) void fm_mlp_kernel(const int* __restrict__ idxL,
                                                     const float* __restrict__ valL,
                                                     const float* __restrict__ emb,
                                                     const float* __restrict__ w1,
                                                     const float* __restrict__ b1,
                                                     const float* __restrict__ w2,
                                                     const float* __restrict__ b2,
                                                     float* __restrict__ inter_out) {
  const int b = blockIdx.x;
  const int tid = threadIdx.x;
  const int kh = tid >> 7;    // 0..3
  const int d  = tid & 127;

  __shared__ float s_se[4][128], s_ssq[4][128];
  __shared__ float s_iv[128], s_h[128];

  float se = 0.f, ssq = 0.f;
  const int kbeg = kh * 75, kend = kbeg + 75;   // 300/4 = 75
  for (int k0 = kbeg; k0 < kend; k0 += 8) {
    int ii[8]; float vv[8];
    #pragma unroll
    for (int u = 0; u < 8; ++u) {
      int k = k0 + u; bool ok = k < kend;
      ii[u] = ok ? idxL[b * TOPK + k] : 0;
      vv[u] = ok ? valL[b * TOPK + k] : 0.f;
    }
    #pragma unroll
    for (int u = 0; u < 8; ++u) {
      float e = emb[(size_t)ii[u] * EMBED_DIM + d];
      float p = vv[u] * e;
      se += p;
      ssq = fmaf(p, p, ssq);
    }
  }
  s_se[kh][d] = se; s_ssq[kh][d] = ssq;
  __syncthreads();

  if (tid < 128) {
    float tse = s_se[0][d] + s_se[1][d] + s_se[2][d] + s_se[3][d];
    float tsq = s_ssq[0][d] + s_ssq[1][d] + s_ssq[2][d] + s_ssq[3][d];
    s_iv[d] = 0.5f * (tse * tse - tsq);
  }
  __syncthreads();

  if (tid < 128) {
    float a = b1[d];
    #pragma unroll 4
    for (int e = 0; e < 128; ++e) a = fmaf(s_iv[e], w1[d * 128 + e], a);
    s_h[d] = fmaxf(a, 0.f);
  }
  __syncthreads();

  #pragma unroll
  for (int r = 0; r < 2; ++r) {
    int j = tid + (r << 9);
    float a = b2[j];
    #pragma unroll 4
    for (int e = 0; e < 128; ++e) a = fmaf(s_h[e], w2[(size_t)j * 128 + e], a);
    inter_out[b * OUT_DIM + j] = a;
  }
}

// ---------------------------------------------------------------------------
// Kernel 3: sparse linear layer. One block per output j (1024 blocks),
// 256 threads = 16 batches x 16 k-slices. All 16 batches' gathers for row j
// run in the same block -> same CU -> same XCD L2: row lines fetched once.
// Also fuses the final output = linear + interaction sum.
// ---------------------------------------------------------------------------
__global__ __launch_bounds__(256) void linear_kernel(const int* __restrict__ idxL,
                                                     const float* __restrict__ valL,
                                                     const float* __restrict__ lin_w,
                                                     const float* __restrict__ lin_b,
                                                     const float* __restrict__ inter_out,
                                                     float* __restrict__ out_sum,
                                                     float* __restrict__ out_lin) {
  const int j = blockIdx.x;
  const int t = threadIdx.x;
  const int b = t >> 4, s = t & 15;
  const float* wrow = lin_w + (size_t)j * F_FEATS;

  int ii[19]; float vv[19];
  #pragma unroll
  for (int u = 0; u < 19; ++u) {
    int k = s + (u << 4);
    bool ok = k < TOPK;
    ii[u] = ok ? idxL[b * TOPK + k] : 0;
    vv[u] = ok ? valL[b * TOPK + k] : 0.f;
  }
  float acc = 0.f;
  #pragma unroll
  for (int u = 0; u < 19; ++u) acc = fmaf(vv[u], wrow[ii[u]], acc);

  acc += __shfl_down(acc, 8, 16);
  acc += __shfl_down(acc, 4, 16);
  acc += __shfl_down(acc, 2, 16);
  acc += __shfl_down(acc, 1, 16);

  if (s == 0) {
    float lo = acc + lin_b[j];
    float sum = lo + inter_out[b * OUT_DIM + j];
    out_lin[b * OUT_DIM + j] = lo;
    out_sum[b * OUT_DIM + j] = sum;
  }
}

extern "C" void kernel_launch(void* const* d_in, const int* in_sizes, int n_in,
                              void* d_out, int out_size, void* d_ws, size_t ws_size,
                              hipStream_t stream) {
  const float* sae   = (const float*)d_in[0];
  const float* emb   = (const float*)d_in[1];
  const float* lin_w = (const float*)d_in[2];
  const float* lin_b = (const float*)d_in[3];
  const float* w1    = (const float*)d_in[4];
  const float* b1    = (const float*)d_in[5];
  const float* w2    = (const float*)d_in[6];
  const float* b2    = (const float*)d_in[7];

  float* out = (float*)d_out;
  float* out_sum = out;                          // output
  float* out_lin = out + BATCH * OUT_DIM;        // linear_out
  float* out_int = out + 2 * BATCH * OUT_DIM;    // interaction_out

  float* valL = (float*)d_ws;
  int*   idxL = (int*)((char*)d_ws + BATCH * TOPK * sizeof(float));

  hipLaunchKernelGGL(topk_kernel, dim3(BATCH), dim3(1024), 0, stream,
                     sae, idxL, valL);
  hipLaunchKernelGGL(fm_mlp_kernel, dim3(BATCH), dim3(512), 0, stream,
                     idxL, valL, emb, w1, b1, w2, b2, out_int);
  hipLaunchKernelGGL(linear_kernel, dim3(OUT_DIM), dim3(256), 0, stream,
                     idxL, valL, lin_w, lin_b, out_int, out_sum, out_lin);
}